// Round 1
// baseline (2393.556 us; speedup 1.0000x reference)
//
#include <hip/hip_runtime.h>

// Micromagnetic LLG + RK4, 128x128 grid, 256 signal steps.
// Key exact simplification: the 100 relaxation steps are a bit-exact no-op
// (uniform m = y-hat gives zero Laplacian, zero demag (mz=0), zero SOT
// (m x p = 0 since m == p)), so m0 = y-hat exactly and m0_z = 0.
// => skip relaxation; probe value = mz_new * Msat.
//
// One kernel per time step. Each block owns a 16x16 tile, stages a 24x24
// halo-4 extended tile in LDS, and computes all 4 RK4 substeps locally
// (substep-k valid regions shrink 22^2 -> 20^2 -> 18^2 -> 16^2), so no
// grid-wide sync is needed inside a step. State is double-buffered in d_ws.

#define GNX 128
#define NPLANE (GNX*GNX)
#define T_STEPS 256

constexpr int TW   = 16;            // interior tile width
constexpr int HALO = 4;             // RK4 dependency radius
constexpr int EXT  = TW + 2*HALO;   // 24
constexpr int NBS  = GNX / TW;      // 8
constexpr int NBLK = NBS * NBS;     // 64
constexpr int NTHR = 256;

// f32 constants mirrored from the reference (computed in double, cast once)
constexpr float F_H    = (float)(175950000000.0 * 1e-13);          // GAMMA*DT
constexpr float F_H6   = (float)(175950000000.0 * 1e-13 / 6.0);
constexpr float F_IDX2 = (float)(1.0 / (5e-09 * 5e-09));           // 1/DX^2
constexpr float F_2A   = (float)(2.0 * 1.3e-11);                   // 2*A_EX
constexpr float F_NMU0 = (float)(-(4e-07 * 3.14159265358979323846)); // -MU0
constexpr float F_CSOT = 0.001f;
constexpr float F_ALPHA= 0.02f;
constexpr float F_CLLG = (float)(-(1.0 / (1.0 + 0.02*0.02)));

struct V3 { float x, y, z; };

__device__ __forceinline__ V3 torque_llg(
    float mx, float my, float mz,
    float sux, float suy, float suz,   // sum of 4 stencil neighbors per comp
    float bx, float by, float bz, float msat)
{
    const float cex = F_2A / msat;
    const float lx = (sux - 4.0f*mx) * F_IDX2;
    const float ly = (suy - 4.0f*my) * F_IDX2;
    const float lz = (suz - 4.0f*mz) * F_IDX2;
    // B_eff = (B_ext + b_exch) + b_demag   (demag only on z)
    const float bex = bx + cex*lx;
    const float bey = by + cex*ly;
    const float bez = (bz + cex*lz) + (F_NMU0*msat)*mz;
    // a = m x B
    const float ax = my*bez - mz*bey;
    const float ay = mz*bex - mx*bez;
    const float az = mx*bey - my*bex;
    // c = m x a
    const float cx = my*az - mz*ay;
    const float cy = mz*ax - mx*az;
    const float cz = mx*ay - my*ax;
    // sot = C_SOT * (m x (m x p)), p = (0,1,0): q = m x p = (-mz, 0, mx)
    const float qx = 0.0f - mz;
    const float qy = 0.0f;
    const float qz = mx;
    const float sx = my*qz - mz*qy;
    const float sy = mz*qx - mx*qz;
    const float sz = mx*qy - my*qx;
    V3 t;
    t.x = F_CLLG*(ax + F_ALPHA*cx) + F_CSOT*sx;
    t.y = F_CLLG*(ay + F_ALPHA*cy) + F_CSOT*sy;
    t.z = F_CLLG*(az + F_ALPHA*cz) + F_CSOT*sz;
    return t;
}

__global__ __launch_bounds__(NTHR) void mm_step(
    const float* __restrict__ m_in, float* __restrict__ m_out,
    const float* __restrict__ signal, const float* __restrict__ B_ext,
    const float* __restrict__ Msat, const int* __restrict__ src_idx,
    const int* __restrict__ probe_idx, float* __restrict__ out,
    int t, int first)
{
    __shared__ float mb[3][EXT][EXT];   // m at step start (pristine)
    __shared__ float tb[3][EXT][EXT];   // current trial field
    __shared__ float ka[3][TW*TW];      // k1 + 2k2 + 2k3 + k4 accumulator

    const int tid = threadIdx.x;
    const int br = blockIdx.x / NBS, bc = blockIdx.x - (blockIdx.x / NBS)*NBS;
    const int r0 = br*TW, c0 = bc*TW;

    // ---- stage m tile (halo clamped to grid edges) ----
    for (int i = tid; i < 3*EXT*EXT; i += NTHR) {
        const int comp = i / (EXT*EXT);
        const int rem  = i - comp*(EXT*EXT);
        const int er = rem / EXT, ec = rem - (rem/EXT)*EXT;
        const int gr = min(max(r0 - HALO + er, 0), GNX-1);
        const int gc = min(max(c0 - HALO + ec, 0), GNX-1);
        float v;
        if (first) v = (comp == 1) ? 1.0f : 0.0f;   // m_init = y-hat
        else       v = m_in[comp*NPLANE + gr*GNX + gc];
        mb[comp][er][ec] = v;
    }
    ka[0][tid] = 0.0f; ka[1][tid] = 0.0f; ka[2][tid] = 0.0f;  // TW*TW == NTHR

    const float sg0 = signal[t*2 + 0];
    const float sg1 = signal[t*2 + 1];
    const int s0r = src_idx[0], s0c = src_idx[1];
    const int s1r = src_idx[2], s1c = src_idx[3];
    __syncthreads();

    // ---- 4 RK4 substeps on shrinking regions ----
    #pragma unroll
    for (int k = 0; k < 4; ++k) {
        const int W   = (k == 0) ? 22 : (k == 1) ? 20 : (k == 2) ? 18 : 16;
        const int off = (EXT - W) / 2;
        const float wk = (k == 1 || k == 2) ? 2.0f : 1.0f;   // accum weight
        const float cc = (k == 2) ? 1.0f : 0.5f;             // trial coeff on H*k

        float trv[2][3];
        int   thas[2] = {0, 0};
        int   ter[2], tec[2];

        for (int ii = 0, i = tid; i < W*W; i += NTHR, ++ii) {
            const int er = off + i / W;
            const int ec = off + (i - (i/W)*W);
            const int gr = r0 - HALO + er, gc = c0 - HALO + ec;
            if (gr < 0 || gr >= GNX || gc < 0 || gc >= GNX) continue;

            // grid-edge clamped stencil coords (in LDS space)
            const int eru = (gr == 0)      ? er : er - 1;
            const int erd = (gr == GNX-1)  ? er : er + 1;
            const int ecl = (gc == 0)      ? ec : ec - 1;
            const int ecr = (gc == GNX-1)  ? ec : ec + 1;

            float mx, my, mz, sux, suy, suz;
            if (k == 0) {
                mx = mb[0][er][ec]; my = mb[1][er][ec]; mz = mb[2][er][ec];
                sux = ((mb[0][erd][ec] + mb[0][eru][ec]) + mb[0][er][ecr]) + mb[0][er][ecl];
                suy = ((mb[1][erd][ec] + mb[1][eru][ec]) + mb[1][er][ecr]) + mb[1][er][ecl];
                suz = ((mb[2][erd][ec] + mb[2][eru][ec]) + mb[2][er][ecr]) + mb[2][er][ecl];
            } else {
                mx = tb[0][er][ec]; my = tb[1][er][ec]; mz = tb[2][er][ec];
                sux = ((tb[0][erd][ec] + tb[0][eru][ec]) + tb[0][er][ecr]) + tb[0][er][ecl];
                suy = ((tb[1][erd][ec] + tb[1][eru][ec]) + tb[1][er][ecr]) + tb[1][er][ecl];
                suz = ((tb[2][erd][ec] + tb[2][eru][ec]) + tb[2][er][ecr]) + tb[2][er][ecl];
            }

            float bx = B_ext[0*NPLANE + gr*GNX + gc];
            float by = B_ext[1*NPLANE + gr*GNX + gc];
            float bz = B_ext[2*NPLANE + gr*GNX + gc];
            if (gr == s0r && gc == s0c) bz = sg0;   // .set semantics,
            if (gr == s1r && gc == s1c) bz = sg1;   // later src wins on dup
            const float msat = Msat[gr*GNX + gc];

            const V3 tq = torque_llg(mx, my, mz, sux, suy, suz, bx, by, bz, msat);

            const int ir = er - HALO, ic = ec - HALO;
            if (ir >= 0 && ir < TW && ic >= 0 && ic < TW) {
                const int idx = ir*TW + ic;
                ka[0][idx] += wk*tq.x;
                ka[1][idx] += wk*tq.y;
                ka[2][idx] += wk*tq.z;
            }
            if (k < 3) {
                trv[ii][0] = mb[0][er][ec] + (F_H*tq.x)*cc;
                trv[ii][1] = mb[1][er][ec] + (F_H*tq.y)*cc;
                trv[ii][2] = mb[2][er][ec] + (F_H*tq.z)*cc;
                thas[ii] = 1; ter[ii] = er; tec[ii] = ec;
            }
        }
        if (k < 3) {
            __syncthreads();   // all trial reads done before overwrite
            #pragma unroll
            for (int ii = 0; ii < 2; ++ii) {
                if (thas[ii]) {
                    tb[0][ter[ii]][tec[ii]] = trv[ii][0];
                    tb[1][ter[ii]][tec[ii]] = trv[ii][1];
                    tb[2][ter[ii]][tec[ii]] = trv[ii][2];
                }
            }
            __syncthreads();
        }
    }
    __syncthreads();

    // ---- final update: one interior cell per thread ----
    {
        const int ir = tid / TW, ic = tid - (tid/TW)*TW;
        const int er = HALO + ir, ec = HALO + ic;
        const int gr = r0 + ir, gc = c0 + ic;
        const float nx = mb[0][er][ec] + F_H6 * ka[0][tid];
        const float ny = mb[1][er][ec] + F_H6 * ka[1][tid];
        const float nz = mb[2][er][ec] + F_H6 * ka[2][tid];
        m_out[0*NPLANE + gr*GNX + gc] = nx;
        m_out[1*NPLANE + gr*GNX + gc] = ny;
        m_out[2*NPLANE + gr*GNX + gc] = nz;
        #pragma unroll
        for (int j = 0; j < 4; ++j) {
            if (gr == probe_idx[2*j] && gc == probe_idx[2*j + 1]) {
                out[t*4 + j] = nz * Msat[gr*GNX + gc];   // m0_z == 0 exactly
            }
        }
    }
}

extern "C" void kernel_launch(void* const* d_in, const int* in_sizes, int n_in,
                              void* d_out, int out_size, void* d_ws, size_t ws_size,
                              hipStream_t stream) {
    const float* sig  = (const float*)d_in[0];
    const float* Bex  = (const float*)d_in[1];
    const float* Ms   = (const float*)d_in[2];
    const int*   srci = (const int*)d_in[3];
    const int*   prbi = (const int*)d_in[4];
    float* out = (float*)d_out;

    float* mA = (float*)d_ws;
    float* mB = mA + 3*NPLANE;

    for (int t = 0; t < T_STEPS; ++t) {
        const float* min_ = (t & 1) ? mB : mA;
        float*       mout = (t & 1) ? mA : mB;
        mm_step<<<NBLK, NTHR, 0, stream>>>(min_, mout, sig, Bex, Ms,
                                           srci, prbi, out, t, t == 0);
    }
}